// Round 1
// baseline (230.359 us; speedup 1.0000x reference)
//
#include <hip/hip_runtime.h>
#include <hip/hip_bf16.h>
#include <math.h>

// Problem constants (from reference): B=16, L=96, H=128.
#define BB 16
#define LL 96
#define HH 128

// Only slice kh=63 of attn_conv_w matters (input height 1, SAME pad (63,64)).
// Only slice kw=63 of cvg_conv_w matters (input width 1, SAME pad (63,64)).

// ---------------- Kernel A: dec_f[b,h], cvg_f[b,o] ----------------
__global__ void prep_kernel(const float* __restrict__ hidden,
                            const float* __restrict__ coverage,
                            const float* __restrict__ cvg_w,
                            const float* __restrict__ cvg_b,
                            const float* __restrict__ dec_w,
                            const float* __restrict__ dec_b,
                            float* __restrict__ dec_f,
                            float* __restrict__ cvg_f) {
    int b = blockIdx.x;
    int t = threadIdx.x;  // 0..127
    __shared__ float hid[HH];
    __shared__ float cov[LL];
    hid[t] = hidden[b * HH + t];
    if (t < LL) cov[t] = coverage[b * LL + t];
    __syncthreads();

    float acc = dec_b[t];
    for (int k = 0; k < HH; ++k) acc += hid[k] * dec_w[t * HH + k];
    dec_f[b * HH + t] = acc;

    if (t < LL) {
        float a2 = cvg_b[t];
        for (int i = 0; i < LL; ++i)
            a2 += cov[i] * cvg_w[(t * LL + i) * HH + 63];
        cvg_f[b * LL + t] = a2;
    }
}

// ---------------- Kernel B: scores[b,o] ----------------
// Grid: (o=96, b=16). Block: 256 threads = 16 i-groups x 16 w-slots.
// Each thread accumulates 8 consecutive w via a rolling 8-register window.
#define EP_PITCH 257   // 255 used entries + pad (odd pitch -> 4-way max conflict)
#define W_PITCH 129    // odd pitch -> conflict-free 4-address broadcast
#define ICHUNK 32

__global__ __launch_bounds__(256) void scores_kernel(
        const float* __restrict__ enc,      // (B, L, H)
        const float* __restrict__ attn_w,   // (L, L, H, H)
        const float* __restrict__ attn_b,   // (L,)
        const float* __restrict__ dec_f,    // (B, H)
        const float* __restrict__ cvg_f,    // (B, L)
        const float* __restrict__ vvec,     // (B, H)
        float* __restrict__ scores) {       // (B, L)
    const int o = blockIdx.x;
    const int b = blockIdx.y;
    const int tid = threadIdx.x;

    __shared__ float encp[ICHUNK * EP_PITCH];  // zero-padded enc rows, t=j+63
    __shared__ float wlds[ICHUNK * W_PITCH];   // W[o, i, 63, m]
    __shared__ float red[16 * HH];             // i-group partials

    const int slot = tid & 15;   // w0 = slot*8
    const int igrp = tid >> 4;   // 0..15
    const int w0 = slot * 8;

    float acc[8];
#pragma unroll
    for (int j = 0; j < 8; ++j) acc[j] = 0.f;

    for (int chunk = 0; chunk < LL / ICHUNK; ++chunk) {
        __syncthreads();
        // stage zero-padded enc rows: encp[r][t] = enc[b, chunk*32+r, t-63] for t in [63,191)
        for (int r = 0; r < ICHUNK; ++r) {
            int i = chunk * ICHUNK + r;
            for (int t = tid; t < 257; t += 256) {
                float val = 0.f;
                if (t >= 63 && t < 191) val = enc[(b * LL + i) * HH + (t - 63)];
                encp[r * EP_PITCH + t] = val;
            }
        }
        // stage W slice rows: wlds[r][m] = attn_w[o, chunk*32+r, 63, m]
        {
            int m = tid & 127;
            for (int r = tid >> 7; r < ICHUNK; r += 2) {
                int i = chunk * ICHUNK + r;
                wlds[r * W_PITCH + m] =
                    attn_w[(((size_t)o * LL + i) * HH + 63) * HH + m];
            }
        }
        __syncthreads();

#pragma unroll
        for (int ii = 0; ii < 2; ++ii) {
            const int rl = igrp * 2 + ii;
            const float* ep = &encp[rl * EP_PITCH + w0];
            const float* wp = &wlds[rl * W_PITCH];
            float r[8];
#pragma unroll
            for (int p = 0; p < 8; ++p) r[p] = ep[p];
            for (int m8 = 0; m8 < HH; m8 += 8) {
#pragma unroll
                for (int k = 0; k < 8; ++k) {
                    const float wv = wp[m8 + k];
#pragma unroll
                    for (int j = 0; j < 8; ++j)
                        acc[j] += r[(k + j) & 7] * wv;
                    // slide window: slot k now holds element m8+k+8
                    r[k] = ep[m8 + k + 8];   // max idx 135+w0 <= 255 < EP_PITCH
                }
            }
        }
    }

    // reduce over 16 i-groups
#pragma unroll
    for (int j = 0; j < 8; ++j) red[igrp * HH + w0 + j] = acc[j];
    __syncthreads();

    float s = 0.f;
    if (tid < HH) {
        float ef = attn_b[o];
        for (int g = 0; g < 16; ++g) ef += red[g * HH + tid];
        ef += dec_f[b * HH + tid] + cvg_f[b * LL + o];
        s = tanhf(ef) * vvec[b * HH + tid];
    }
    __syncthreads();
    // block reduce (all 256 threads participate; s=0 for tid>=128)
#pragma unroll
    for (int off = 32; off > 0; off >>= 1) s += __shfl_down(s, off, 64);
    if ((tid & 63) == 0) red[tid >> 6] = s;
    __syncthreads();
    if (tid == 0) scores[b * LL + o] = red[0] + red[1] + red[2] + red[3];
}

// ---------------- Kernel C: softmax + outputs ----------------
__global__ void finalize_kernel(const float* __restrict__ scores,
                                const float* __restrict__ coverage,
                                const float* __restrict__ enc,
                                float* __restrict__ out) {
    int b = blockIdx.x;
    int t = threadIdx.x;  // 0..127
    __shared__ float sc[LL];
    __shared__ float at[LL];
    if (t < LL) sc[t] = scores[b * LL + t];
    __syncthreads();

    float mx = -1e30f;
    for (int l = 0; l < LL; ++l) mx = fmaxf(mx, sc[l]);
    float sum = 0.f;
    for (int l = 0; l < LL; ++l) sum += expf(sc[l] - mx);

    if (t < LL) {
        float a = expf(sc[t] - mx) / sum;
        at[t] = a;
        out[BB * HH + b * LL + t] = a;                            // attn
        out[BB * HH + BB * LL + b * LL + t] = coverage[b * LL + t] + a;  // new_coverage
    }
    __syncthreads();

    float ctx = 0.f;
    for (int l = 0; l < LL; ++l) ctx += at[l] * enc[(b * LL + l) * HH + t];
    out[b * HH + t] = ctx;                                        // context
}

extern "C" void kernel_launch(void* const* d_in, const int* in_sizes, int n_in,
                              void* d_out, int out_size, void* d_ws, size_t ws_size,
                              hipStream_t stream) {
    const float* hidden   = (const float*)d_in[0];
    const float* enc      = (const float*)d_in[1];
    const float* coverage = (const float*)d_in[2];
    const float* attn_w   = (const float*)d_in[3];
    const float* attn_b   = (const float*)d_in[4];
    const float* cvg_w    = (const float*)d_in[5];
    const float* cvg_b    = (const float*)d_in[6];
    const float* dec_w    = (const float*)d_in[7];
    const float* dec_b    = (const float*)d_in[8];
    const float* vvec     = (const float*)d_in[9];
    float* out = (float*)d_out;

    float* ws = (float*)d_ws;
    float* dec_f  = ws;                    // B*H   = 2048
    float* cvg_f  = ws + BB * HH;          // B*L   = 1536
    float* scores = ws + BB * HH + BB * LL; // B*L  = 1536

    prep_kernel<<<BB, HH, 0, stream>>>(hidden, coverage, cvg_w, cvg_b,
                                       dec_w, dec_b, dec_f, cvg_f);
    scores_kernel<<<dim3(LL, BB), 256, 0, stream>>>(enc, attn_w, attn_b,
                                                    dec_f, cvg_f, vvec, scores);
    finalize_kernel<<<BB, HH, 0, stream>>>(scores, coverage, enc, out);
}

// Round 2
// 86.856 us; speedup vs baseline: 2.6522x; 2.6522x over previous
//
#include <hip/hip_runtime.h>
#include <hip/hip_bf16.h>
#include <math.h>

// Problem constants (from reference): B=16, L=96, H=128.
#define BB 16
#define LL 96
#define HH 128

// Only slice kh=63 of attn_conv_w matters (input height 1, SAME pad (63,64)).
// Only slice kw=63 of cvg_conv_w matters (input width 1, SAME pad (63,64)).

// ---------------- Kernel A: dec_f[b,h], cvg_f[b,o] ----------------
__global__ void prep_kernel(const float* __restrict__ hidden,
                            const float* __restrict__ coverage,
                            const float* __restrict__ cvg_w,
                            const float* __restrict__ cvg_b,
                            const float* __restrict__ dec_w,
                            const float* __restrict__ dec_b,
                            float* __restrict__ dec_f,
                            float* __restrict__ cvg_f) {
    int b = blockIdx.x;
    int t = threadIdx.x;  // 0..127
    __shared__ float hid[HH];
    __shared__ float cov[LL];
    hid[t] = hidden[b * HH + t];
    if (t < LL) cov[t] = coverage[b * LL + t];
    __syncthreads();

    float acc = dec_b[t];
    for (int k = 0; k < HH; ++k) acc += hid[k] * dec_w[t * HH + k];
    dec_f[b * HH + t] = acc;

    if (t < LL) {
        float a2 = cvg_b[t];
        for (int i = 0; i < LL; ++i)
            a2 += cov[i] * cvg_w[(t * LL + i) * HH + 63];
        cvg_f[b * LL + t] = a2;
    }
}

// ---------------- Kernel B: scores[b,o] ----------------
// Grid (o=96, b=16), 256 threads = 8 w-slots (16 w each) x 32 groups
// (16 i-rows x 2 m-halves). Rolling 32-float circular register window,
// all LDS traffic as ds_read_b128.
#define ICH 16
#define NCH (LL / ICH)      // 6
#define EPITCH 260          // mult of 4 (b128-aligned); 260%32=4 -> balanced banks
#define WPITCH 132          // mult of 4; 132%32=4 -> distinct broadcast rows

__global__ __launch_bounds__(256, 6) void scores_kernel(
        const float* __restrict__ enc,      // (B, L, H)
        const float* __restrict__ attn_w,   // (L, L, H, H)
        const float* __restrict__ attn_b,   // (L,)
        const float* __restrict__ dec_f,    // (B, H)
        const float* __restrict__ cvg_f,    // (B, L)
        const float* __restrict__ vvec,     // (B, H)
        float* __restrict__ scores) {       // (B, L)
    const int o = blockIdx.x;
    const int b = blockIdx.y;
    const int tid = threadIdx.x;

    __shared__ float sEnc[ICH * EPITCH];   // zero-padded rows: [63,191) = enc
    __shared__ float sW[ICH * WPITCH];     // W[o, i, 63, :]

    const int slot = tid & 7;     // w0 = slot*16
    const int g    = tid >> 3;    // 0..31
    const int row  = g & 15;      // i-row within chunk
    const int mh   = g >> 4;      // m-half: m base = mh*64

    // zero-fill pads once (interior gets overwritten every chunk)
    for (int i = tid; i < ICH * EPITCH; i += 256) sEnc[i] = 0.f;

    float acc[16];
#pragma unroll
    for (int j = 0; j < 16; ++j) acc[j] = 0.f;

    const int stg_r = tid >> 7;    // 0..1
    const int stg_c = tid & 127;
    const size_t encBase = (size_t)b * LL * HH;

    for (int ch = 0; ch < NCH; ++ch) {
        __syncthreads();
        const int i0 = ch * ICH;
#pragma unroll
        for (int rr = 0; rr < 8; ++rr) {
            const int r = rr * 2 + stg_r;
            sEnc[r * EPITCH + 63 + stg_c] =
                enc[encBase + (size_t)(i0 + r) * HH + stg_c];
            sW[r * WPITCH + stg_c] =
                attn_w[((size_t)(o * LL + i0 + r) * HH + 63) * HH + stg_c];
        }
        __syncthreads();

        const float* epb = &sEnc[row * EPITCH + slot * 16 + mh * 64];
        const float* wpb = &sW[row * WPITCH + mh * 64];

        float win[32];
        *(float4*)&win[0]  = *(const float4*)&epb[0];
        *(float4*)&win[4]  = *(const float4*)&epb[4];
        *(float4*)&win[8]  = *(const float4*)&epb[8];
        *(float4*)&win[12] = *(const float4*)&epb[12];
#pragma unroll
        for (int it = 0; it < 8; ++it) {
            const int base = it * 8;
            *(float4*)&win[(base + 16) & 31] = *(const float4*)&epb[base + 16];
            *(float4*)&win[(base + 20) & 31] = *(const float4*)&epb[base + 20];
            float wv[8];
            *(float4*)&wv[0] = *(const float4*)&wpb[base];
            *(float4*)&wv[4] = *(const float4*)&wpb[base + 4];
#pragma unroll
            for (int k = 0; k < 8; ++k) {
#pragma unroll
                for (int j = 0; j < 16; ++j)
                    acc[j] += win[(base + k + j) & 31] * wv[k];
            }
        }
    }

    // reduce over 32 groups (alias red onto sEnc; compute is done)
    __syncthreads();
    float* red = sEnc;
#pragma unroll
    for (int q = 0; q < 4; ++q) {
        float4 t;
        t.x = acc[q * 4 + 0]; t.y = acc[q * 4 + 1];
        t.z = acc[q * 4 + 2]; t.w = acc[q * 4 + 3];
        *(float4*)&red[g * 128 + slot * 16 + q * 4] = t;
    }
    __syncthreads();

    float s = 0.f;
    if (tid < HH) {
        float ef = attn_b[o] + dec_f[b * HH + tid] + cvg_f[b * LL + o];
#pragma unroll
        for (int gg = 0; gg < 32; ++gg) ef += red[gg * 128 + tid];
        s = tanhf(ef) * vvec[b * HH + tid];
    }
#pragma unroll
    for (int off = 32; off > 0; off >>= 1) s += __shfl_down(s, off, 64);
    if ((tid & 63) == 0) sW[tid >> 6] = s;
    __syncthreads();
    if (tid == 0) scores[b * LL + o] = sW[0] + sW[1] + sW[2] + sW[3];
}

// ---------------- Kernel C: softmax + outputs ----------------
__global__ void finalize_kernel(const float* __restrict__ scores,
                                const float* __restrict__ coverage,
                                const float* __restrict__ enc,
                                float* __restrict__ out) {
    int b = blockIdx.x;
    int t = threadIdx.x;  // 0..127
    __shared__ float sc[LL];
    __shared__ float at[LL];
    if (t < LL) sc[t] = scores[b * LL + t];
    __syncthreads();

    float mx = -1e30f;
    for (int l = 0; l < LL; ++l) mx = fmaxf(mx, sc[l]);
    float sum = 0.f;
    for (int l = 0; l < LL; ++l) sum += expf(sc[l] - mx);

    if (t < LL) {
        float a = expf(sc[t] - mx) / sum;
        at[t] = a;
        out[BB * HH + b * LL + t] = a;                                   // attn
        out[BB * HH + BB * LL + b * LL + t] = coverage[b * LL + t] + a;  // new_coverage
    }
    __syncthreads();

    float ctx = 0.f;
    for (int l = 0; l < LL; ++l) ctx += at[l] * enc[(b * LL + l) * HH + t];
    out[b * HH + t] = ctx;                                               // context
}

extern "C" void kernel_launch(void* const* d_in, const int* in_sizes, int n_in,
                              void* d_out, int out_size, void* d_ws, size_t ws_size,
                              hipStream_t stream) {
    const float* hidden   = (const float*)d_in[0];
    const float* enc      = (const float*)d_in[1];
    const float* coverage = (const float*)d_in[2];
    const float* attn_w   = (const float*)d_in[3];
    const float* attn_b   = (const float*)d_in[4];
    const float* cvg_w    = (const float*)d_in[5];
    const float* cvg_b    = (const float*)d_in[6];
    const float* dec_w    = (const float*)d_in[7];
    const float* dec_b    = (const float*)d_in[8];
    const float* vvec     = (const float*)d_in[9];
    float* out = (float*)d_out;

    float* ws = (float*)d_ws;
    float* dec_f  = ws;                      // B*H = 2048
    float* cvg_f  = ws + BB * HH;            // B*L = 1536
    float* scores = ws + BB * HH + BB * LL;  // B*L = 1536

    prep_kernel<<<BB, HH, 0, stream>>>(hidden, coverage, cvg_w, cvg_b,
                                       dec_w, dec_b, dec_f, cvg_f);
    scores_kernel<<<dim3(LL, BB), 256, 0, stream>>>(enc, attn_w, attn_b,
                                                    dec_f, cvg_f, vvec, scores);
    finalize_kernel<<<BB, HH, 0, stream>>>(scores, coverage, enc, out);
}

// Round 3
// 49.083 us; speedup vs baseline: 4.6932x; 1.7696x over previous
//
#include <hip/hip_runtime.h>
#include <hip/hip_bf16.h>
#include <math.h>

// Problem constants: B=16, L=96, H=128.
#define BB 16
#define LL 96
#define HH 128

typedef __attribute__((ext_vector_type(8))) short short8;
typedef __attribute__((ext_vector_type(4))) float f32x4;

// Only slice kh=63 of attn_conv_w matters (input height 1, SAME pad (63,64)).
// Only slice kw=63 of cvg_conv_w matters (input width 1, SAME pad (63,64)).
//
// ws layout (float units):
#define WS_W    0              // 589824 float-slots = 1179648 shorts: bf16 W [i][o][e] (e pre-XOR-swizzled)
#define WS_E    589824         // 16*96*256 fp32 zero-padded enc rows [b][i][256] (t=63..190 = enc)
#define WS_DEC  983040         // 16*128
#define WS_CVG  985088         // 16*96
#define WS_SC   986624         // 16*96
#define WS_P    988160         // 32*16*96*128 split-K partials

// ---------------- P1: convert W->bf16 (swizzled), build padded enc, dec_f, cvg_f ----------------
__global__ __launch_bounds__(256) void prep_kernel(
        const float* __restrict__ hidden,
        const float* __restrict__ enc,
        const float* __restrict__ coverage,
        const float* __restrict__ attn_w,
        const float* __restrict__ cvg_w,
        const float* __restrict__ cvg_b,
        const float* __restrict__ dec_w,
        const float* __restrict__ dec_b,
        float* __restrict__ ws) {
    const int bid = blockIdx.x;
    const int tid = threadIdx.x;
    if (bid < 96) {
        // W slice: ws_W[i][o][e] = bf16(attn_w[o][i][63][ e ^ ((o&7)<<3) ])
        const int i = bid;
        unsigned short* wout = (unsigned short*)(ws + WS_W);
        for (int idx = tid; idx < LL * HH; idx += 256) {
            const int o = idx >> 7, e = idx & 127;
            const int esrc = e ^ ((o & 7) << 3);
            float v = attn_w[(((size_t)o * LL + i) * HH + 63) * HH + esrc];
            __hip_bfloat16 h = __float2bfloat16(v);
            wout[(size_t)i * LL * HH + idx] = *(unsigned short*)&h;
        }
    } else if (bid < 112) {
        // padded enc rows: ws_E[b][i][t] = enc[b][i][t-63] for t in [63,191), else 0
        const int b = bid - 96;
        float* eout = ws + WS_E + (size_t)b * LL * 256;
        for (int idx = tid; idx < LL * 256; idx += 256) {
            const int i = idx >> 8, t = idx & 255;
            eout[idx] = (t >= 63 && t < 191) ? enc[((size_t)b * LL + i) * HH + (t - 63)] : 0.f;
        }
    } else {
        const int b = bid - 112;
        __shared__ float hid[HH];
        __shared__ float cov[LL];
        if (tid < HH) hid[tid] = hidden[b * HH + tid];
        if (tid < LL) cov[tid] = coverage[b * LL + tid];
        __syncthreads();
        if (tid < HH) {
            float acc = dec_b[tid];
            for (int k = 0; k < HH; ++k) acc += hid[k] * dec_w[tid * HH + k];
            ws[WS_DEC + b * HH + tid] = acc;
        } else if (tid < HH + LL) {
            const int t = tid - HH;
            float a2 = cvg_b[t];
            for (int i2 = 0; i2 < LL; ++i2)
                a2 += cov[i2] * cvg_w[((size_t)t * LL + i2) * HH + 63];
            ws[WS_CVG + b * LL + t] = a2;
        }
    }
}

// ---------------- M: split-K implicit-im2col bf16 MFMA GEMM ----------------
// grid (kc=32, b=16); 256 threads = 4 waves; wave wg covers w in [wg*32, wg*32+32).
// Each wave: 6 o-tiles x 2 w-tiles of 16x16x32 MFMA; k-chunk = 3 i-rows = 12 k-steps.
__global__ __launch_bounds__(256) void mfma_kernel(float* __restrict__ ws) {
    const int kc = blockIdx.x;   // 0..31
    const int b  = blockIdx.y;   // 0..15
    const int tid  = threadIdx.x;
    const int lane = tid & 63;
    const int wg   = tid >> 6;   // wave id 0..3
    const int lo   = lane & 15;
    const int hi   = lane >> 4;  // 0..3

    __shared__ __align__(16) short Abuf[LL * HH];  // 24KB, bf16 W[o][e] (e swizzled)
    __shared__ __align__(16) float Ebuf[256];      // padded enc row (fp32)

    f32x4 acc[6][2];
#pragma unroll
    for (int a = 0; a < 6; ++a)
#pragma unroll
        for (int c = 0; c < 2; ++c) acc[a][c] = f32x4{0.f, 0.f, 0.f, 0.f};

    const short* wsrc = (const short*)(ws + WS_W);
    const float* esrc = ws + WS_E + (size_t)b * LL * 256;

    for (int ii = 0; ii < 3; ++ii) {
        const int ig = kc * 3 + ii;   // global i row
        __syncthreads();
        // stage A: 12288 shorts = 1536 short8, 6 per thread
        {
            const short8* s8 = (const short8*)(wsrc + (size_t)ig * LL * HH);
            short8* d8 = (short8*)Abuf;
#pragma unroll
            for (int t = 0; t < 6; ++t) d8[tid + t * 256] = s8[tid + t * 256];
            if (tid < 64)
                ((float4*)Ebuf)[tid] = ((const float4*)(esrc + ig * 256))[tid];
        }
        __syncthreads();

#pragma unroll
        for (int s = 0; s < 4; ++s) {      // k-step within i (m0 = 32s)
            short8 af[6];
#pragma unroll
            for (int ot = 0; ot < 6; ++ot) {
                const int o = ot * 16 + lo;
                const int idx8 = o * 16 + (((s << 2) + hi) ^ (o & 7));
                af[ot] = ((const short8*)Abuf)[idx8];
            }
#pragma unroll
            for (int wt = 0; wt < 2; ++wt) {
                const int t0 = s * 32 + hi * 8 + wg * 32 + wt * 16 + lo;  // <= 247
                union { short8 s8; __hip_bfloat16 h[8]; } bf;
#pragma unroll
                for (int j = 0; j < 8; ++j) bf.h[j] = __float2bfloat16(Ebuf[t0 + j]);
#pragma unroll
                for (int ot = 0; ot < 6; ++ot)
                    acc[ot][wt] = __builtin_amdgcn_mfma_f32_16x16x32_bf16(
                        af[ot], bf.s8, acc[ot][wt], 0, 0, 0);
            }
        }
    }

    // write split-K partials
    float* dst = ws + WS_P + ((size_t)kc * BB + b) * LL * HH;
#pragma unroll
    for (int ot = 0; ot < 6; ++ot)
#pragma unroll
        for (int wt = 0; wt < 2; ++wt)
#pragma unroll
            for (int r = 0; r < 4; ++r) {
                const int o = ot * 16 + hi * 4 + r;     // C/D: row=(lane>>4)*4+reg
                const int w = wg * 32 + wt * 16 + lo;   //      col=lane&15
                dst[o * HH + w] = acc[ot][wt][r];
            }
}

// ---------------- R: sum partials + bias/dec/cvg -> tanh -> dot v -> scores ----------------
__global__ __launch_bounds__(128) void reduce_kernel(
        const float* __restrict__ attn_b,
        const float* __restrict__ vvec,
        float* __restrict__ ws) {
    const int o = blockIdx.x;   // 0..95
    const int b = blockIdx.y;   // 0..15
    const int h = threadIdx.x;  // 0..127
    const float* p = ws + WS_P + (size_t)b * LL * HH + o * HH + h;
    float sum = 0.f;
#pragma unroll
    for (int kc = 0; kc < 32; ++kc) sum += p[(size_t)kc * BB * LL * HH];
    float ef = sum + attn_b[o] + ws[WS_DEC + b * HH + h] + ws[WS_CVG + b * LL + o];
    float s = tanhf(ef) * vvec[b * HH + h];
#pragma unroll
    for (int off = 32; off > 0; off >>= 1) s += __shfl_down(s, off, 64);
    __shared__ float r2[2];
    if ((h & 63) == 0) r2[h >> 6] = s;
    __syncthreads();
    if (h == 0) ws[WS_SC + b * LL + o] = r2[0] + r2[1];
}

// ---------------- F: softmax + outputs ----------------
__global__ void finalize_kernel(const float* __restrict__ ws_scores,
                                const float* __restrict__ coverage,
                                const float* __restrict__ enc,
                                float* __restrict__ out) {
    int b = blockIdx.x;
    int t = threadIdx.x;  // 0..127
    __shared__ float sc[LL];
    __shared__ float at[LL];
    if (t < LL) sc[t] = ws_scores[b * LL + t];
    __syncthreads();

    float mx = -1e30f;
    for (int l = 0; l < LL; ++l) mx = fmaxf(mx, sc[l]);
    float sum = 0.f;
    for (int l = 0; l < LL; ++l) sum += expf(sc[l] - mx);

    if (t < LL) {
        float a = expf(sc[t] - mx) / sum;
        at[t] = a;
        out[BB * HH + b * LL + t] = a;                                   // attn
        out[BB * HH + BB * LL + b * LL + t] = coverage[b * LL + t] + a;  // new_coverage
    }
    __syncthreads();

    float ctx = 0.f;
    for (int l = 0; l < LL; ++l) ctx += at[l] * enc[(b * LL + l) * HH + t];
    out[b * HH + t] = ctx;                                               // context
}

extern "C" void kernel_launch(void* const* d_in, const int* in_sizes, int n_in,
                              void* d_out, int out_size, void* d_ws, size_t ws_size,
                              hipStream_t stream) {
    const float* hidden   = (const float*)d_in[0];
    const float* enc      = (const float*)d_in[1];
    const float* coverage = (const float*)d_in[2];
    const float* attn_w   = (const float*)d_in[3];
    const float* attn_b   = (const float*)d_in[4];
    const float* cvg_w    = (const float*)d_in[5];
    const float* cvg_b    = (const float*)d_in[6];
    const float* dec_w    = (const float*)d_in[7];
    const float* dec_b    = (const float*)d_in[8];
    const float* vvec     = (const float*)d_in[9];
    float* out = (float*)d_out;
    float* ws = (float*)d_ws;

    prep_kernel<<<128, 256, 0, stream>>>(hidden, enc, coverage, attn_w,
                                         cvg_w, cvg_b, dec_w, dec_b, ws);
    mfma_kernel<<<dim3(32, BB), 256, 0, stream>>>(ws);
    reduce_kernel<<<dim3(LL, BB), 128, 0, stream>>>(attn_b, vvec, ws);
    finalize_kernel<<<BB, HH, 0, stream>>>(ws + WS_SC, coverage, enc, out);
}